// Round 1
// baseline (513.565 us; speedup 1.0000x reference)
//
#include <hip/hip_runtime.h>
#include <math.h>

#define NPOS 65536          // D*H*W = 16*64*64
#define DD 16
#define HHH 64
#define WWW 64
#define NCHUNK 128

// ---------------- K0: transpose weights to [in][out] layouts ----------------
__global__ void k0_transpose(const float* __restrict__ Wq, const float* __restrict__ Wr,
                             const float* __restrict__ Wf, const float* __restrict__ Wp,
                             float* __restrict__ Wqt, float* __restrict__ Wrt,
                             float* __restrict__ Wft, float* __restrict__ Wpt) {
    int idx = blockIdx.x * 256 + threadIdx.x;
    if (idx < 192*64) { int oc = idx / 64, ic = idx % 64; Wqt[ic*192 + oc] = Wq[idx]; }
    int i2 = idx - 192*64;
    if (i2 >= 0 && i2 < 64*64) { int oc = i2 / 64, c = i2 % 64; Wrt[c*64 + oc] = Wr[i2]; }
    int i3 = i2 - 64*64;
    if (i3 >= 0 && i3 < 64*128) { int oc = i3 / 128, c = i3 % 128; Wft[c*64 + oc] = Wf[i3]; }
    int i4 = i3 - 64*128;
    if (i4 >= 0 && i4 < 64*64) { int oc = i4 / 64, c = i4 % 64; Wpt[c*64 + oc] = Wp[i4]; }
}

// ---------------- K1: pointwise qkv conv (192 out x 64 in) ----------------
// grid 512 blocks (256 pos each), 256 threads; xs[ic][pos] in LDS.
__global__ __launch_bounds__(256) void k1_qkv(const float* __restrict__ x,
        const float* __restrict__ Wqt, const float* __restrict__ bq,
        float* __restrict__ qkv) {
    __shared__ float xs[64 * 256];
    const int tid = threadIdx.x;
    const int blk = blockIdx.x;
    const int b = blk >> 8;                 // 256 blocks per batch
    const int n0 = (blk & 255) << 8;
    const float* xb = x + ((long long)b * 64) * NPOS + n0;
    for (int ic = 0; ic < 64; ++ic)
        xs[ic * 256 + tid] = xb[(long long)ic * NPOS + tid];
    __syncthreads();
    float* outb = qkv + ((long long)b * 192) * NPOS + n0 + tid;
    for (int chunk = 0; chunk < 3; ++chunk) {
        float acc[64];
        #pragma unroll
        for (int o = 0; o < 64; ++o) acc[o] = bq[chunk * 64 + o];
        for (int ic = 0; ic < 64; ++ic) {
            float xv = xs[ic * 256 + tid];
            #pragma unroll
            for (int o = 0; o < 64; ++o)
                acc[o] = fmaf(Wqt[ic * 192 + chunk * 64 + o], xv, acc[o]);
        }
        #pragma unroll
        for (int o = 0; o < 64; ++o)
            outb[(long long)(chunk * 64 + o) * NPOS] = acc[o];
    }
}

// ---------------- K2: depthwise 3x3x3 conv, groups=192, pad=1 ----------------
__global__ __launch_bounds__(256) void k2_dw(const float* __restrict__ qkv,
        const float* __restrict__ Wd, const float* __restrict__ bd,
        float* __restrict__ qkv2) {
    const int idx = blockIdx.x * 256 + threadIdx.x;   // over 2*192*65536
    const int n = idx & 65535;
    const int bc = idx >> 16;                          // b*192 + c
    const int c = bc % 192;
    const int d = n >> 12, h = (n >> 6) & 63, w = n & 63;
    const float* in = qkv + (long long)bc * NPOS;
    const float* wd = Wd + c * 27;
    float acc = bd[c];
    #pragma unroll
    for (int kd = 0; kd < 3; ++kd) {
        int di = d + kd - 1;
        if (di < 0 || di >= DD) continue;
        #pragma unroll
        for (int kh = 0; kh < 3; ++kh) {
            int hi = h + kh - 1;
            if (hi < 0 || hi >= HHH) continue;
            #pragma unroll
            for (int kw = 0; kw < 3; ++kw) {
                int wi = w + kw - 1;
                if (wi < 0 || wi >= WWW) continue;
                acc = fmaf(wd[kd * 9 + kh * 3 + kw], in[(di << 12) + (hi << 6) + wi], acc);
            }
        }
    }
    qkv2[idx] = acc;
}

// ---------------- K3: Gram partials: per (b,h,chunk) -> 64 qk + 8 qq + 8 kk ----------------
__global__ __launch_bounds__(256) void k3_gram(const float* __restrict__ qkv2,
                                               float* __restrict__ partial) {
    const int blk = blockIdx.x;
    const int chunk = blk & (NCHUNK - 1);
    const int bh = blk >> 7;                  // 0..15
    const int b = bh >> 3, h = bh & 7;
    const float* qb = qkv2 + ((long long)b * 192 + h * 8) * NPOS;
    const float* kb = qb + 64 * NPOS;
    const int npc = NPOS / NCHUNK;            // 512
    const int n0 = chunk * npc;
    float vals[80];
    #pragma unroll
    for (int s = 0; s < 80; ++s) vals[s] = 0.f;
    for (int t = threadIdx.x; t < npc; t += 256) {
        int n = n0 + t;
        float qv[8], kv[8];
        #pragma unroll
        for (int i = 0; i < 8; ++i) qv[i] = qb[i * NPOS + n];
        #pragma unroll
        for (int j = 0; j < 8; ++j) kv[j] = kb[j * NPOS + n];
        #pragma unroll
        for (int i = 0; i < 8; ++i) {
            #pragma unroll
            for (int j = 0; j < 8; ++j)
                vals[i * 8 + j] = fmaf(qv[i], kv[j], vals[i * 8 + j]);
        }
        #pragma unroll
        for (int i = 0; i < 8; ++i) vals[64 + i] = fmaf(qv[i], qv[i], vals[64 + i]);
        #pragma unroll
        for (int j = 0; j < 8; ++j) vals[72 + j] = fmaf(kv[j], kv[j], vals[72 + j]);
    }
    __shared__ float red[4][80];
    const int lane = threadIdx.x & 63, wv = threadIdx.x >> 6;
    #pragma unroll
    for (int s = 0; s < 80; ++s) {
        float v = vals[s];
        #pragma unroll
        for (int off = 32; off > 0; off >>= 1)
            v += __shfl_xor(v, off, 64);
        if (lane == 0) red[wv][s] = v;
    }
    __syncthreads();
    if (threadIdx.x < 80)
        partial[((long long)bh * NCHUNK + chunk) * 80 + threadIdx.x] =
            red[0][threadIdx.x] + red[1][threadIdx.x] + red[2][threadIdx.x] + red[3][threadIdx.x];
}

// ---------------- K3b: deterministic chunk reduction ----------------
__global__ void k3b_reduce(const float* __restrict__ partial, float* __restrict__ gram) {
    int s = blockIdx.x * 256 + threadIdx.x;
    if (s >= 16 * 80) return;
    int bh = s / 80, slot = s % 80;
    float acc = 0.f;
    for (int c = 0; c < NCHUNK; ++c)
        acc += partial[((long long)bh * NCHUNK + c) * 80 + slot];
    gram[s] = acc;
}

// ---------------- K4: attn -> topk mask softmax -> combined P ----------------
__global__ void k4_combine(const float* __restrict__ gram, const float* __restrict__ temp,
                           const float* __restrict__ aw, float* __restrict__ P) {
    int t = threadIdx.x;               // one (b,h,i) row per thread; 128 threads
    if (t >= 128) return;
    int bh = t >> 3, i = t & 7;
    int h = bh & 7;
    const float* g = gram + bh * 80;
    float qn = fmaxf(sqrtf(g[64 + i]), 1e-12f);
    float tp = temp[h];
    float attn[8];
    #pragma unroll
    for (int j = 0; j < 8; ++j) {
        float kn = fmaxf(sqrtf(g[72 + j]), 1e-12f);
        attn[j] = g[i * 8 + j] / (qn * kn) * tp;
    }
    float awv[4];
    float am = -3.4e38f;
    for (int r = 0; r < 4; ++r) { awv[r] = aw[r]; am = fmaxf(am, awv[r]); }
    float asum = 0.f;
    for (int r = 0; r < 4; ++r) { awv[r] = expf(awv[r] - am); asum += awv[r]; }
    const int kvs[4] = {4, 5, 6, 6};   // int(8*ratio) for 0.5,0.67,0.75,0.8
    float Pacc[8];
    #pragma unroll
    for (int j = 0; j < 8; ++j) Pacc[j] = 0.f;
    for (int r = 0; r < 4; ++r) {
        float sw = awv[r] / asum;
        int kv = kvs[r];
        bool sel[8];
        #pragma unroll
        for (int j = 0; j < 8; ++j) sel[j] = false;
        for (int m = 0; m < kv; ++m) {     // exact top_k: ties -> smallest index
            int best = 0; float bv = -3.4e38f;
            for (int j = 0; j < 8; ++j)
                if (!sel[j] && attn[j] > bv) { bv = attn[j]; best = j; }
            sel[best] = true;
        }
        float mx = -3.4e38f;
        for (int j = 0; j < 8; ++j) if (sel[j]) mx = fmaxf(mx, attn[j]);
        float es = 0.f, e[8];
        for (int j = 0; j < 8; ++j) { e[j] = sel[j] ? expf(attn[j] - mx) : 0.f; es += e[j]; }
        for (int j = 0; j < 8; ++j) Pacc[j] += sw * e[j] / es;
    }
    for (int j = 0; j < 8; ++j) P[t * 8 + j] = Pacc[j];
}

// ---------------- K5: fused tail: weighted -> recalib -> enhanced -> fus(bn2) -> proj ----------------
// block = 64 positions; 256 threads = (16 pos-groups of 4) x (16 ch-groups of 4)
__global__ __launch_bounds__(256) void k5_tail(
        const float* __restrict__ qkv2, const float* __restrict__ x,
        const float* __restrict__ P,
        const float* __restrict__ Wrt, const float* __restrict__ br,
        const float* __restrict__ bn1g, const float* __restrict__ bn1b,
        const float* __restrict__ Wft, const float* __restrict__ bfu,
        const float* __restrict__ bn2g, const float* __restrict__ bn2b,
        const float* __restrict__ Wpt, const float* __restrict__ bp,
        float* __restrict__ out) {
    __shared__ __align__(16) float Xs[64 * 64];
    __shared__ __align__(16) float As[64 * 64];
    __shared__ __align__(16) float Bs[64 * 64];
    __shared__ float Pl[512];
    const int tid = threadIdx.x;
    const int blk = blockIdx.x;
    const int b = blk >> 10;                 // 1024 blocks per batch
    const int n0 = (blk & 1023) << 6;
    const float* vg = qkv2 + ((long long)b * 192 + 128) * NPOS + n0;
    const float* xg = x + ((long long)b * 64) * NPOS + n0;
    #pragma unroll
    for (int k = 0; k < 4; ++k) {
        int idx = tid + k * 256;             // 1024 float4 tiles of [64ch][64pos]
        int ch = idx >> 4, p = (idx & 15) << 2;
        *(float4*)(As + ch * 64 + p) = *(const float4*)(vg + (long long)ch * NPOS + p);
        *(float4*)(Xs + ch * 64 + p) = *(const float4*)(xg + (long long)ch * NPOS + p);
    }
    Pl[tid] = P[b * 512 + tid];
    Pl[tid + 256] = P[b * 512 + 256 + tid];
    __syncthreads();

    const int pg = tid & 15, cg = tid >> 4;
    const int p4 = pg << 2;
    const int hd = cg >> 1;                  // head of our 4 channels
    const float invs = 1.0f / sqrtf(1.0f + 1e-5f);

    // ---- weighted = P @ v  -> Bs
    {
        float acc[4][4];
        #pragma unroll
        for (int u = 0; u < 4; ++u)
            #pragma unroll
            for (int q = 0; q < 4; ++q) acc[u][q] = 0.f;
        #pragma unroll
        for (int j = 0; j < 8; ++j) {
            float4 v4 = *(float4*)(As + (hd * 8 + j) * 64 + p4);
            float vv[4] = {v4.x, v4.y, v4.z, v4.w};
            #pragma unroll
            for (int u = 0; u < 4; ++u) {
                float pv = Pl[hd * 64 + ((4 * cg + u) & 7) * 8 + j];
                #pragma unroll
                for (int q = 0; q < 4; ++q) acc[u][q] = fmaf(pv, vv[q], acc[u][q]);
            }
        }
        #pragma unroll
        for (int u = 0; u < 4; ++u)
            *(float4*)(Bs + (4 * cg + u) * 64 + p4) =
                make_float4(acc[u][0], acc[u][1], acc[u][2], acc[u][3]);
    }
    __syncthreads();

    // ---- recalib = sigmoid(bn1(Wr @ weighted + br)); enhanced -> As
    float rec[4][4];
    {
        float a2[4][4];
        #pragma unroll
        for (int u = 0; u < 4; ++u) {
            float bias = br[4 * cg + u];
            #pragma unroll
            for (int q = 0; q < 4; ++q) a2[u][q] = bias;
        }
        for (int c = 0; c < 64; ++c) {
            float4 bv = *(float4*)(Bs + c * 64 + p4);
            float4 wv = *(const float4*)(Wrt + c * 64 + 4 * cg);
            float bvv[4] = {bv.x, bv.y, bv.z, bv.w};
            float wvv[4] = {wv.x, wv.y, wv.z, wv.w};
            #pragma unroll
            for (int u = 0; u < 4; ++u)
                #pragma unroll
                for (int q = 0; q < 4; ++q)
                    a2[u][q] = fmaf(wvv[u], bvv[q], a2[u][q]);
        }
        #pragma unroll
        for (int u = 0; u < 4; ++u) {
            int oc = 4 * cg + u;
            float s = bn1g[oc] * invs, tt = bn1b[oc];
            #pragma unroll
            for (int q = 0; q < 4; ++q) {
                float z = fmaf(a2[u][q], s, tt);
                rec[u][q] = 1.f / (1.f + expf(-z));
            }
        }
    }
    #pragma unroll
    for (int u = 0; u < 4; ++u) {
        float4 bv = *(float4*)(Bs + (4 * cg + u) * 64 + p4);
        *(float4*)(As + (4 * cg + u) * 64 + p4) =
            make_float4(bv.x * rec[u][0], bv.y * rec[u][1], bv.z * rec[u][2], bv.w * rec[u][3]);
    }
    __syncthreads();

    // ---- fus = bn2(Wf @ [enhanced; x] + bf) -> Bs
    {
        float a2[4][4];
        #pragma unroll
        for (int u = 0; u < 4; ++u) {
            float bias = bfu[4 * cg + u];
            #pragma unroll
            for (int q = 0; q < 4; ++q) a2[u][q] = bias;
        }
        for (int c = 0; c < 64; ++c) {
            float4 av = *(float4*)(As + c * 64 + p4);
            float4 w1 = *(const float4*)(Wft + c * 64 + 4 * cg);
            float avv[4] = {av.x, av.y, av.z, av.w};
            float w1v[4] = {w1.x, w1.y, w1.z, w1.w};
            #pragma unroll
            for (int u = 0; u < 4; ++u)
                #pragma unroll
                for (int q = 0; q < 4; ++q)
                    a2[u][q] = fmaf(w1v[u], avv[q], a2[u][q]);
            float4 xv = *(float4*)(Xs + c * 64 + p4);
            float4 w2 = *(const float4*)(Wft + (64 + c) * 64 + 4 * cg);
            float xvv[4] = {xv.x, xv.y, xv.z, xv.w};
            float w2v[4] = {w2.x, w2.y, w2.z, w2.w};
            #pragma unroll
            for (int u = 0; u < 4; ++u)
                #pragma unroll
                for (int q = 0; q < 4; ++q)
                    a2[u][q] = fmaf(w2v[u], xvv[q], a2[u][q]);
        }
        #pragma unroll
        for (int u = 0; u < 4; ++u) {
            int oc = 4 * cg + u;
            float s = bn2g[oc] * invs, tt = bn2b[oc];
            #pragma unroll
            for (int q = 0; q < 4; ++q) a2[u][q] = fmaf(a2[u][q], s, tt);
            *(float4*)(Bs + oc * 64 + p4) =
                make_float4(a2[u][0], a2[u][1], a2[u][2], a2[u][3]);
        }
    }
    __syncthreads();

    // ---- proj -> out
    {
        float a2[4][4];
        #pragma unroll
        for (int u = 0; u < 4; ++u) {
            float bias = bp[4 * cg + u];
            #pragma unroll
            for (int q = 0; q < 4; ++q) a2[u][q] = bias;
        }
        for (int c = 0; c < 64; ++c) {
            float4 bv = *(float4*)(Bs + c * 64 + p4);
            float4 wv = *(const float4*)(Wpt + c * 64 + 4 * cg);
            float bvv[4] = {bv.x, bv.y, bv.z, bv.w};
            float wvv[4] = {wv.x, wv.y, wv.z, wv.w};
            #pragma unroll
            for (int u = 0; u < 4; ++u)
                #pragma unroll
                for (int q = 0; q < 4; ++q)
                    a2[u][q] = fmaf(wvv[u], bvv[q], a2[u][q]);
        }
        #pragma unroll
        for (int u = 0; u < 4; ++u)
            *(float4*)(out + ((long long)b * 64 + 4 * cg + u) * NPOS + n0 + p4) =
                make_float4(a2[u][0], a2[u][1], a2[u][2], a2[u][3]);
    }
}

extern "C" void kernel_launch(void* const* d_in, const int* in_sizes, int n_in,
                              void* d_out, int out_size, void* d_ws, size_t ws_size,
                              hipStream_t stream) {
    (void)in_sizes; (void)n_in; (void)out_size; (void)ws_size;
    const float* x     = (const float*)d_in[0];
    const float* w_qkv = (const float*)d_in[1];
    const float* b_qkv = (const float*)d_in[2];
    const float* w_dw  = (const float*)d_in[3];
    const float* b_dw  = (const float*)d_in[4];
    const float* temp  = (const float*)d_in[5];
    const float* aw    = (const float*)d_in[6];
    const float* w_rec = (const float*)d_in[7];
    const float* b_rec = (const float*)d_in[8];
    const float* bn1g  = (const float*)d_in[9];
    const float* bn1b  = (const float*)d_in[10];
    const float* w_fus = (const float*)d_in[11];
    const float* b_fus = (const float*)d_in[12];
    const float* bn2g  = (const float*)d_in[13];
    const float* bn2b  = (const float*)d_in[14];
    const float* w_prj = (const float*)d_in[15];
    const float* b_prj = (const float*)d_in[16];
    float* out = (float*)d_out;
    float* ws  = (float*)d_ws;

    float* qkv  = ws;                       // 2*192*65536 = 25165824 floats
    float* qkv2 = qkv + 25165824;           // 25165824 floats
    float* part = qkv2 + 25165824;          // 16*128*80 = 163840
    float* gram = part + 163840;            // 1280
    float* P    = gram + 1280;              // 1024
    float* Wqt  = P + 1024;                 // 12288
    float* Wrt  = Wqt + 12288;              // 4096
    float* Wft  = Wrt + 4096;               // 8192
    float* Wpt  = Wft + 8192;               // 4096  (total ~202.1 MB)

    k0_transpose<<<112, 256, 0, stream>>>(w_qkv, w_rec, w_fus, w_prj, Wqt, Wrt, Wft, Wpt);
    k1_qkv<<<512, 256, 0, stream>>>(x, Wqt, b_qkv, qkv);
    k2_dw<<<98304, 256, 0, stream>>>(qkv, w_dw, b_dw, qkv2);
    k3_gram<<<16 * NCHUNK, 256, 0, stream>>>(qkv2, part);
    k3b_reduce<<<5, 256, 0, stream>>>(part, gram);
    k4_combine<<<1, 128, 0, stream>>>(gram, temp, aw, P);
    k5_tail<<<2048, 256, 0, stream>>>(qkv2, x, P, Wrt, b_rec, bn1g, bn1b,
                                      Wft, b_fus, bn2g, bn2b, Wpt, b_prj, out);
}

// Round 2
// 375.955 us; speedup vs baseline: 1.3660x; 1.3660x over previous
//
#include <hip/hip_runtime.h>
#include <math.h>

#define NPOS 65536          // D*H*W = 16*64*64
#define DD 16
#define HHH 64
#define WWW 64
#define NCHUNK 128

// ---------------- K0: transpose weights to [in][out] layouts ----------------
__global__ void k0_transpose(const float* __restrict__ Wq, const float* __restrict__ Wr,
                             const float* __restrict__ Wf, const float* __restrict__ Wp,
                             float* __restrict__ Wqt, float* __restrict__ Wrt,
                             float* __restrict__ Wft, float* __restrict__ Wpt) {
    int idx = blockIdx.x * 256 + threadIdx.x;
    if (idx < 192*64) { int oc = idx / 64, ic = idx % 64; Wqt[ic*192 + oc] = Wq[idx]; }
    int i2 = idx - 192*64;
    if (i2 >= 0 && i2 < 64*64) { int oc = i2 / 64, c = i2 % 64; Wrt[c*64 + oc] = Wr[i2]; }
    int i3 = i2 - 64*64;
    if (i3 >= 0 && i3 < 64*128) { int oc = i3 / 128, c = i3 % 128; Wft[c*64 + oc] = Wf[i3]; }
    int i4 = i3 - 64*128;
    if (i4 >= 0 && i4 < 64*64) { int oc = i4 / 64, c = i4 % 64; Wpt[c*64 + oc] = Wp[i4]; }
}

// ---------------- K1: pointwise qkv conv (192 out x 64 in) ----------------
// grid 512 blocks (256 pos each), 256 threads; xs[ic][pos] in LDS.
__global__ __launch_bounds__(256) void k1_qkv(const float* __restrict__ x,
        const float* __restrict__ Wqt, const float* __restrict__ bq,
        float* __restrict__ qkv) {
    __shared__ float xs[64 * 256];
    const int tid = threadIdx.x;
    const int blk = blockIdx.x;
    const int b = blk >> 8;                 // 256 blocks per batch
    const int n0 = (blk & 255) << 8;
    const float* xb = x + ((long long)b * 64) * NPOS + n0;
    for (int ic = 0; ic < 64; ++ic)
        xs[ic * 256 + tid] = xb[(long long)ic * NPOS + tid];
    __syncthreads();
    float* outb = qkv + ((long long)b * 192) * NPOS + n0 + tid;
    for (int chunk = 0; chunk < 3; ++chunk) {
        float acc[64];
        #pragma unroll
        for (int o = 0; o < 64; ++o) acc[o] = bq[chunk * 64 + o];
        for (int ic = 0; ic < 64; ++ic) {
            float xv = xs[ic * 256 + tid];
            #pragma unroll
            for (int o = 0; o < 64; ++o)
                acc[o] = fmaf(Wqt[ic * 192 + chunk * 64 + o], xv, acc[o]);
        }
        #pragma unroll
        for (int o = 0; o < 64; ++o)
            outb[(long long)(chunk * 64 + o) * NPOS] = acc[o];
    }
}

// ---------------- K2: depthwise 3x3x3 conv, groups=192, pad=1 ----------------
// 16-lane group owns one (bc,d,h) row of 64 w; 4 outputs/lane via float4.
// Weights are block-uniform -> LDS broadcast. Block = 256 thr = 16 rows.
__global__ __launch_bounds__(256) void k2_dw(const float* __restrict__ qkv,
        const float* __restrict__ Wd, const float* __restrict__ bd,
        float* __restrict__ qkv2) {
    const int tid = threadIdx.x;
    const int wl  = tid & 15;               // lane within row-group
    const int g   = tid >> 4;               // row-group 0..15
    const int bc  = blockIdx.x >> 6;        // 64 blocks per (b,c)
    const int r   = ((blockIdx.x & 63) << 4) + g;   // 0..1023
    const int d   = r >> 6, h = r & 63;
    const int c   = bc % 192;               // uniform per block

    __shared__ float wsh[27];
    __shared__ float bsh[1];
    if (tid < 27) wsh[tid] = Wd[c * 27 + tid];
    if (tid == 31) bsh[0] = bd[c];
    __syncthreads();

    const float* in = qkv + (long long)bc * NPOS;
    const int w0 = wl << 2;
    float acc0 = bsh[0], acc1 = bsh[0], acc2 = bsh[0], acc3 = bsh[0];

    #pragma unroll
    for (int kd = 0; kd < 3; ++kd) {
        const int di = d + kd - 1;
        if (di < 0 || di >= DD) continue;
        #pragma unroll
        for (int kh = 0; kh < 3; ++kh) {
            const int hi = h + kh - 1;
            if (hi < 0 || hi >= HHH) continue;
            const float* row = in + (di << 12) + (hi << 6);
            const float4 v = *(const float4*)(row + w0);
            const float lf = (wl > 0)  ? row[w0 - 1] : 0.f;
            const float rt = (wl < 15) ? row[w0 + 4] : 0.f;
            const float W0 = wsh[kd * 9 + kh * 3 + 0];
            const float W1 = wsh[kd * 9 + kh * 3 + 1];
            const float W2 = wsh[kd * 9 + kh * 3 + 2];
            acc0 = fmaf(W0, lf,  fmaf(W1, v.x, fmaf(W2, v.y, acc0)));
            acc1 = fmaf(W0, v.x, fmaf(W1, v.y, fmaf(W2, v.z, acc1)));
            acc2 = fmaf(W0, v.y, fmaf(W1, v.z, fmaf(W2, v.w, acc2)));
            acc3 = fmaf(W0, v.z, fmaf(W1, v.w, fmaf(W2, rt,  acc3)));
        }
    }
    *(float4*)(qkv2 + (long long)bc * NPOS + (d << 12) + (h << 6) + w0) =
        make_float4(acc0, acc1, acc2, acc3);
}

// ---------------- K3: Gram partials: per (b,h,chunk) -> 64 qk + 8 qq + 8 kk ----------------
__global__ __launch_bounds__(256) void k3_gram(const float* __restrict__ qkv2,
                                               float* __restrict__ partial) {
    const int blk = blockIdx.x;
    const int chunk = blk & (NCHUNK - 1);
    const int bh = blk >> 7;                  // 0..15
    const int b = bh >> 3, h = bh & 7;
    const float* qb = qkv2 + ((long long)b * 192 + h * 8) * NPOS;
    const float* kb = qb + 64 * NPOS;
    const int npc = NPOS / NCHUNK;            // 512
    const int n0 = chunk * npc;
    float vals[80];
    #pragma unroll
    for (int s = 0; s < 80; ++s) vals[s] = 0.f;
    for (int t = threadIdx.x; t < npc; t += 256) {
        int n = n0 + t;
        float qv[8], kv[8];
        #pragma unroll
        for (int i = 0; i < 8; ++i) qv[i] = qb[i * NPOS + n];
        #pragma unroll
        for (int j = 0; j < 8; ++j) kv[j] = kb[j * NPOS + n];
        #pragma unroll
        for (int i = 0; i < 8; ++i) {
            #pragma unroll
            for (int j = 0; j < 8; ++j)
                vals[i * 8 + j] = fmaf(qv[i], kv[j], vals[i * 8 + j]);
        }
        #pragma unroll
        for (int i = 0; i < 8; ++i) vals[64 + i] = fmaf(qv[i], qv[i], vals[64 + i]);
        #pragma unroll
        for (int j = 0; j < 8; ++j) vals[72 + j] = fmaf(kv[j], kv[j], vals[72 + j]);
    }
    __shared__ float red[4][80];
    const int lane = threadIdx.x & 63, wv = threadIdx.x >> 6;
    #pragma unroll
    for (int s = 0; s < 80; ++s) {
        float v = vals[s];
        #pragma unroll
        for (int off = 32; off > 0; off >>= 1)
            v += __shfl_xor(v, off, 64);
        if (lane == 0) red[wv][s] = v;
    }
    __syncthreads();
    if (threadIdx.x < 80)
        partial[((long long)bh * NCHUNK + chunk) * 80 + threadIdx.x] =
            red[0][threadIdx.x] + red[1][threadIdx.x] + red[2][threadIdx.x] + red[3][threadIdx.x];
}

// ---------------- K3b: deterministic chunk reduction ----------------
__global__ void k3b_reduce(const float* __restrict__ partial, float* __restrict__ gram) {
    int s = blockIdx.x * 256 + threadIdx.x;
    if (s >= 16 * 80) return;
    int bh = s / 80, slot = s % 80;
    float acc = 0.f;
    for (int c = 0; c < NCHUNK; ++c)
        acc += partial[((long long)bh * NCHUNK + c) * 80 + slot];
    gram[s] = acc;
}

// ---------------- K4: attn -> topk mask softmax -> combined P ----------------
__global__ void k4_combine(const float* __restrict__ gram, const float* __restrict__ temp,
                           const float* __restrict__ aw, float* __restrict__ P) {
    int t = threadIdx.x;               // one (b,h,i) row per thread; 128 threads
    if (t >= 128) return;
    int bh = t >> 3, i = t & 7;
    int h = bh & 7;
    const float* g = gram + bh * 80;
    float qn = fmaxf(sqrtf(g[64 + i]), 1e-12f);
    float tp = temp[h];
    float attn[8];
    #pragma unroll
    for (int j = 0; j < 8; ++j) {
        float kn = fmaxf(sqrtf(g[72 + j]), 1e-12f);
        attn[j] = g[i * 8 + j] / (qn * kn) * tp;
    }
    float awv[4];
    float am = -3.4e38f;
    for (int r = 0; r < 4; ++r) { awv[r] = aw[r]; am = fmaxf(am, awv[r]); }
    float asum = 0.f;
    for (int r = 0; r < 4; ++r) { awv[r] = expf(awv[r] - am); asum += awv[r]; }
    const int kvs[4] = {4, 5, 6, 6};   // int(8*ratio) for 0.5,0.67,0.75,0.8
    float Pacc[8];
    #pragma unroll
    for (int j = 0; j < 8; ++j) Pacc[j] = 0.f;
    for (int r = 0; r < 4; ++r) {
        float sw = awv[r] / asum;
        int kv = kvs[r];
        bool sel[8];
        #pragma unroll
        for (int j = 0; j < 8; ++j) sel[j] = false;
        for (int m = 0; m < kv; ++m) {     // exact top_k: ties -> smallest index
            int best = 0; float bv = -3.4e38f;
            for (int j = 0; j < 8; ++j)
                if (!sel[j] && attn[j] > bv) { bv = attn[j]; best = j; }
            sel[best] = true;
        }
        float mx = -3.4e38f;
        for (int j = 0; j < 8; ++j) if (sel[j]) mx = fmaxf(mx, attn[j]);
        float es = 0.f, e[8];
        for (int j = 0; j < 8; ++j) { e[j] = sel[j] ? expf(attn[j] - mx) : 0.f; es += e[j]; }
        for (int j = 0; j < 8; ++j) Pacc[j] += sw * e[j] / es;
    }
    for (int j = 0; j < 8; ++j) P[t * 8 + j] = Pacc[j];
}

// ---------------- K5: fused tail: weighted -> recalib -> enhanced -> fus(bn2) -> proj ----------------
// block = 64 positions; 256 threads = (16 pos-groups of 4) x (16 ch-groups of 4)
__global__ __launch_bounds__(256) void k5_tail(
        const float* __restrict__ qkv2, const float* __restrict__ x,
        const float* __restrict__ P,
        const float* __restrict__ Wrt, const float* __restrict__ br,
        const float* __restrict__ bn1g, const float* __restrict__ bn1b,
        const float* __restrict__ Wft, const float* __restrict__ bfu,
        const float* __restrict__ bn2g, const float* __restrict__ bn2b,
        const float* __restrict__ Wpt, const float* __restrict__ bp,
        float* __restrict__ out) {
    __shared__ __align__(16) float Xs[64 * 64];
    __shared__ __align__(16) float As[64 * 64];
    __shared__ __align__(16) float Bs[64 * 64];
    __shared__ float Pl[512];
    const int tid = threadIdx.x;
    const int blk = blockIdx.x;
    const int b = blk >> 10;                 // 1024 blocks per batch
    const int n0 = (blk & 1023) << 6;
    const float* vg = qkv2 + ((long long)b * 192 + 128) * NPOS + n0;
    const float* xg = x + ((long long)b * 64) * NPOS + n0;
    #pragma unroll
    for (int k = 0; k < 4; ++k) {
        int idx = tid + k * 256;             // 1024 float4 tiles of [64ch][64pos]
        int ch = idx >> 4, p = (idx & 15) << 2;
        *(float4*)(As + ch * 64 + p) = *(const float4*)(vg + (long long)ch * NPOS + p);
        *(float4*)(Xs + ch * 64 + p) = *(const float4*)(xg + (long long)ch * NPOS + p);
    }
    Pl[tid] = P[b * 512 + tid];
    Pl[tid + 256] = P[b * 512 + 256 + tid];
    __syncthreads();

    const int pg = tid & 15, cg = tid >> 4;
    const int p4 = pg << 2;
    const int hd = cg >> 1;                  // head of our 4 channels
    const float invs = 1.0f / sqrtf(1.0f + 1e-5f);

    // ---- weighted = P @ v  -> Bs
    {
        float acc[4][4];
        #pragma unroll
        for (int u = 0; u < 4; ++u)
            #pragma unroll
            for (int q = 0; q < 4; ++q) acc[u][q] = 0.f;
        #pragma unroll
        for (int j = 0; j < 8; ++j) {
            float4 v4 = *(float4*)(As + (hd * 8 + j) * 64 + p4);
            float vv[4] = {v4.x, v4.y, v4.z, v4.w};
            #pragma unroll
            for (int u = 0; u < 4; ++u) {
                float pv = Pl[hd * 64 + ((4 * cg + u) & 7) * 8 + j];
                #pragma unroll
                for (int q = 0; q < 4; ++q) acc[u][q] = fmaf(pv, vv[q], acc[u][q]);
            }
        }
        #pragma unroll
        for (int u = 0; u < 4; ++u)
            *(float4*)(Bs + (4 * cg + u) * 64 + p4) =
                make_float4(acc[u][0], acc[u][1], acc[u][2], acc[u][3]);
    }
    __syncthreads();

    // ---- recalib = sigmoid(bn1(Wr @ weighted + br)); enhanced -> As
    float rec[4][4];
    {
        float a2[4][4];
        #pragma unroll
        for (int u = 0; u < 4; ++u) {
            float bias = br[4 * cg + u];
            #pragma unroll
            for (int q = 0; q < 4; ++q) a2[u][q] = bias;
        }
        for (int c = 0; c < 64; ++c) {
            float4 bv = *(float4*)(Bs + c * 64 + p4);
            float4 wv = *(const float4*)(Wrt + c * 64 + 4 * cg);
            float bvv[4] = {bv.x, bv.y, bv.z, bv.w};
            float wvv[4] = {wv.x, wv.y, wv.z, wv.w};
            #pragma unroll
            for (int u = 0; u < 4; ++u)
                #pragma unroll
                for (int q = 0; q < 4; ++q)
                    a2[u][q] = fmaf(wvv[u], bvv[q], a2[u][q]);
        }
        #pragma unroll
        for (int u = 0; u < 4; ++u) {
            int oc = 4 * cg + u;
            float s = bn1g[oc] * invs, tt = bn1b[oc];
            #pragma unroll
            for (int q = 0; q < 4; ++q) {
                float z = fmaf(a2[u][q], s, tt);
                rec[u][q] = 1.f / (1.f + expf(-z));
            }
        }
    }
    #pragma unroll
    for (int u = 0; u < 4; ++u) {
        float4 bv = *(float4*)(Bs + (4 * cg + u) * 64 + p4);
        *(float4*)(As + (4 * cg + u) * 64 + p4) =
            make_float4(bv.x * rec[u][0], bv.y * rec[u][1], bv.z * rec[u][2], bv.w * rec[u][3]);
    }
    __syncthreads();

    // ---- fus = bn2(Wf @ [enhanced; x] + bf) -> Bs
    {
        float a2[4][4];
        #pragma unroll
        for (int u = 0; u < 4; ++u) {
            float bias = bfu[4 * cg + u];
            #pragma unroll
            for (int q = 0; q < 4; ++q) a2[u][q] = bias;
        }
        for (int c = 0; c < 64; ++c) {
            float4 av = *(float4*)(As + c * 64 + p4);
            float4 w1 = *(const float4*)(Wft + c * 64 + 4 * cg);
            float avv[4] = {av.x, av.y, av.z, av.w};
            float w1v[4] = {w1.x, w1.y, w1.z, w1.w};
            #pragma unroll
            for (int u = 0; u < 4; ++u)
                #pragma unroll
                for (int q = 0; q < 4; ++q)
                    a2[u][q] = fmaf(w1v[u], avv[q], a2[u][q]);
            float4 xv = *(float4*)(Xs + c * 64 + p4);
            float4 w2 = *(const float4*)(Wft + (64 + c) * 64 + 4 * cg);
            float xvv[4] = {xv.x, xv.y, xv.z, xv.w};
            float w2v[4] = {w2.x, w2.y, w2.z, w2.w};
            #pragma unroll
            for (int u = 0; u < 4; ++u)
                #pragma unroll
                for (int q = 0; q < 4; ++q)
                    a2[u][q] = fmaf(w2v[u], xvv[q], a2[u][q]);
        }
        #pragma unroll
        for (int u = 0; u < 4; ++u) {
            int oc = 4 * cg + u;
            float s = bn2g[oc] * invs, tt = bn2b[oc];
            #pragma unroll
            for (int q = 0; q < 4; ++q) a2[u][q] = fmaf(a2[u][q], s, tt);
            *(float4*)(Bs + oc * 64 + p4) =
                make_float4(a2[u][0], a2[u][1], a2[u][2], a2[u][3]);
        }
    }
    __syncthreads();

    // ---- proj -> out
    {
        float a2[4][4];
        #pragma unroll
        for (int u = 0; u < 4; ++u) {
            float bias = bp[4 * cg + u];
            #pragma unroll
            for (int q = 0; q < 4; ++q) a2[u][q] = bias;
        }
        for (int c = 0; c < 64; ++c) {
            float4 bv = *(float4*)(Bs + c * 64 + p4);
            float4 wv = *(const float4*)(Wpt + c * 64 + 4 * cg);
            float bvv[4] = {bv.x, bv.y, bv.z, bv.w};
            float wvv[4] = {wv.x, wv.y, wv.z, wv.w};
            #pragma unroll
            for (int u = 0; u < 4; ++u)
                #pragma unroll
                for (int q = 0; q < 4; ++q)
                    a2[u][q] = fmaf(wvv[u], bvv[q], a2[u][q]);
        }
        #pragma unroll
        for (int u = 0; u < 4; ++u)
            *(float4*)(out + ((long long)b * 64 + 4 * cg + u) * NPOS + n0 + p4) =
                make_float4(a2[u][0], a2[u][1], a2[u][2], a2[u][3]);
    }
}

extern "C" void kernel_launch(void* const* d_in, const int* in_sizes, int n_in,
                              void* d_out, int out_size, void* d_ws, size_t ws_size,
                              hipStream_t stream) {
    (void)in_sizes; (void)n_in; (void)out_size; (void)ws_size;
    const float* x     = (const float*)d_in[0];
    const float* w_qkv = (const float*)d_in[1];
    const float* b_qkv = (const float*)d_in[2];
    const float* w_dw  = (const float*)d_in[3];
    const float* b_dw  = (const float*)d_in[4];
    const float* temp  = (const float*)d_in[5];
    const float* aw    = (const float*)d_in[6];
    const float* w_rec = (const float*)d_in[7];
    const float* b_rec = (const float*)d_in[8];
    const float* bn1g  = (const float*)d_in[9];
    const float* bn1b  = (const float*)d_in[10];
    const float* w_fus = (const float*)d_in[11];
    const float* b_fus = (const float*)d_in[12];
    const float* bn2g  = (const float*)d_in[13];
    const float* bn2b  = (const float*)d_in[14];
    const float* w_prj = (const float*)d_in[15];
    const float* b_prj = (const float*)d_in[16];
    float* out = (float*)d_out;
    float* ws  = (float*)d_ws;

    float* qkv  = ws;                       // 2*192*65536 = 25165824 floats
    float* qkv2 = qkv + 25165824;           // 25165824 floats
    float* part = qkv2 + 25165824;          // 16*128*80 = 163840
    float* gram = part + 163840;            // 1280
    float* P    = gram + 1280;              // 1024
    float* Wqt  = P + 1024;                 // 12288
    float* Wrt  = Wqt + 12288;              // 4096
    float* Wft  = Wrt + 4096;               // 8192
    float* Wpt  = Wft + 8192;               // 4096  (total ~202.1 MB)

    k0_transpose<<<112, 256, 0, stream>>>(w_qkv, w_rec, w_fus, w_prj, Wqt, Wrt, Wft, Wpt);
    k1_qkv<<<512, 256, 0, stream>>>(x, Wqt, b_qkv, qkv);
    k2_dw<<<24576, 256, 0, stream>>>(qkv, w_dw, b_dw, qkv2);
    k3_gram<<<16 * NCHUNK, 256, 0, stream>>>(qkv2, part);
    k3b_reduce<<<5, 256, 0, stream>>>(part, gram);
    k4_combine<<<1, 128, 0, stream>>>(gram, temp, aw, P);
    k5_tail<<<2048, 256, 0, stream>>>(qkv2, x, P, Wrt, b_rec, bn1g, bn1b,
                                      Wft, b_fus, bn2g, bn2b, Wpt, b_prj, out);
}

// Round 3
// 303.309 us; speedup vs baseline: 1.6932x; 1.2395x over previous
//
#include <hip/hip_runtime.h>
#include <math.h>

#define NPOS 65536          // D*H*W = 16*64*64
#define DD 16
#define HHH 64
#define WWW 64
#define NCHUNK 128

// ---------------- K0: transpose weights to [in][out] layouts ----------------
__global__ void k0_transpose(const float* __restrict__ Wq, const float* __restrict__ Wr,
                             const float* __restrict__ Wf, const float* __restrict__ Wp,
                             float* __restrict__ Wqt, float* __restrict__ Wrt,
                             float* __restrict__ Wft, float* __restrict__ Wpt) {
    int idx = blockIdx.x * 256 + threadIdx.x;
    if (idx < 192*64) { int oc = idx / 64, ic = idx % 64; Wqt[ic*192 + oc] = Wq[idx]; }
    int i2 = idx - 192*64;
    if (i2 >= 0 && i2 < 64*64) { int oc = i2 / 64, c = i2 % 64; Wrt[c*64 + oc] = Wr[i2]; }
    int i3 = i2 - 64*64;
    if (i3 >= 0 && i3 < 64*128) { int oc = i3 / 128, c = i3 % 128; Wft[c*64 + oc] = Wf[i3]; }
    int i4 = i3 - 64*128;
    if (i4 >= 0 && i4 < 64*64) { int oc = i4 / 64, c = i4 % 64; Wpt[c*64 + oc] = Wp[i4]; }
}

// ---------------- K1: pointwise qkv conv (192 out x 64 in) ----------------
__global__ __launch_bounds__(256) void k1_qkv(const float* __restrict__ x,
        const float* __restrict__ Wqt, const float* __restrict__ bq,
        float* __restrict__ qkv) {
    __shared__ float xs[64 * 256];
    const int tid = threadIdx.x;
    const int blk = blockIdx.x;
    const int b = blk >> 8;                 // 256 blocks per batch
    const int n0 = (blk & 255) << 8;
    const float* xb = x + ((long long)b * 64) * NPOS + n0;
    for (int ic = 0; ic < 64; ++ic)
        xs[ic * 256 + tid] = xb[(long long)ic * NPOS + tid];
    __syncthreads();
    float* outb = qkv + ((long long)b * 192) * NPOS + n0 + tid;
    for (int chunk = 0; chunk < 3; ++chunk) {
        float acc[64];
        #pragma unroll
        for (int o = 0; o < 64; ++o) acc[o] = bq[chunk * 64 + o];
        for (int ic = 0; ic < 64; ++ic) {
            float xv = xs[ic * 256 + tid];
            #pragma unroll
            for (int o = 0; o < 64; ++o)
                acc[o] = fmaf(Wqt[ic * 192 + chunk * 64 + o], xv, acc[o]);
        }
        #pragma unroll
        for (int o = 0; o < 64; ++o)
            outb[(long long)(chunk * 64 + o) * NPOS] = acc[o];
    }
}

// ---------------- K2: depthwise 3x3x3 conv via LDS stencil tile ----------------
// Block: 256 thr -> output tile (4d x 16h x 64w) of one (b,c).
// LDS tile: 6d x 18h x 84-stride rows (w halo = zero columns at idx 3 and 68).
// Thread: 2 d-rows x 8 w outputs; 12 tap-rows x 4 ds_read_b128 (conflict-free
// by stride-84: bank group = (21r + 2wg + k) mod 8 uniform).
__global__ __launch_bounds__(256) void k2_dw(const float* __restrict__ qkv,
        const float* __restrict__ Wd, const float* __restrict__ bd,
        float* __restrict__ qkv2) {
    __shared__ __align__(16) float tile[108 * 84];
    __shared__ float wsh[28];
    const int tid = threadIdx.x;
    const int bc  = blockIdx.x >> 4;        // 0..383 = b*192 + c
    const int sub = blockIdx.x & 15;
    const int d0  = (sub >> 2) << 2;        // 0,4,8,12
    const int h0  = (sub & 3) << 4;         // 0,16,32,48
    const int c   = bc % 192;

    if (tid < 27) wsh[tid] = Wd[c * 27 + tid];
    if (tid == 31) wsh[27] = bd[c];

    const float* in = qkv + (long long)bc * NPOS;
    // zero w-halo columns (global w=-1 and w=64 are zero padding)
    for (int r = tid; r < 108; r += 256) {
        tile[r * 84 + 3]  = 0.f;
        tile[r * 84 + 68] = 0.f;
    }
    // stage 108 rows x 16 quads
    for (int i = tid; i < 1728; i += 256) {
        const int r = i >> 4, q = i & 15;
        const int dd = r / 18;              // 0..5
        const int hh = r - dd * 18;         // 0..17
        const int d = d0 + dd - 1;
        const int h = h0 + hh - 1;
        float4 v = make_float4(0.f, 0.f, 0.f, 0.f);
        if (d >= 0 && d < DD && h >= 0 && h < HHH)
            v = *(const float4*)(in + (d << 12) + (h << 6) + (q << 2));
        *(float4*)(tile + r * 84 + 4 + (q << 2)) = v;
    }
    __syncthreads();

    float wreg[27];
    #pragma unroll
    for (int s = 0; s < 27; ++s) wreg[s] = wsh[s];
    const float bias = wsh[27];

    const int wg  = tid & 7;
    const int w0  = wg << 3;                // 8 outputs along w
    const int rid = tid >> 3;               // 0..31
    const int oh  = rid & 15;               // 0..15
    const int od  = (rid >> 4) << 1;        // 0 or 2 (d-pair base)

    float acc0[8], acc1[8];
    #pragma unroll
    for (int j = 0; j < 8; ++j) { acc0[j] = bias; acc1[j] = bias; }

    #pragma unroll
    for (int kh = 0; kh < 3; ++kh) {
        #pragma unroll
        for (int dd = 0; dd < 4; ++dd) {
            const float* row = tile + ((od + dd) * 18 + oh + kh) * 84 + w0;
            const float4 q0 = *(const float4*)(row);
            const float4 q1 = *(const float4*)(row + 4);
            const float4 q2 = *(const float4*)(row + 8);
            const float4 q3 = *(const float4*)(row + 12);
            const float e0 = q0.w, e1 = q1.x, e2 = q1.y, e3 = q1.z, e4 = q1.w;
            const float e5 = q2.x, e6 = q2.y, e7 = q2.z, e8 = q2.w, e9 = q3.x;
            const float ee[10] = {e0,e1,e2,e3,e4,e5,e6,e7,e8,e9};
            if (dd < 3) {
                const float W0 = wreg[dd * 9 + kh * 3 + 0];
                const float W1 = wreg[dd * 9 + kh * 3 + 1];
                const float W2 = wreg[dd * 9 + kh * 3 + 2];
                #pragma unroll
                for (int j = 0; j < 8; ++j)
                    acc0[j] = fmaf(W0, ee[j], fmaf(W1, ee[j+1], fmaf(W2, ee[j+2], acc0[j])));
            }
            if (dd > 0) {
                const float W0 = wreg[(dd-1) * 9 + kh * 3 + 0];
                const float W1 = wreg[(dd-1) * 9 + kh * 3 + 1];
                const float W2 = wreg[(dd-1) * 9 + kh * 3 + 2];
                #pragma unroll
                for (int j = 0; j < 8; ++j)
                    acc1[j] = fmaf(W0, ee[j], fmaf(W1, ee[j+1], fmaf(W2, ee[j+2], acc1[j])));
            }
        }
    }
    float* outp = qkv2 + (long long)bc * NPOS + ((d0 + od) << 12) + ((h0 + oh) << 6) + w0;
    *(float4*)(outp)          = make_float4(acc0[0], acc0[1], acc0[2], acc0[3]);
    *(float4*)(outp + 4)      = make_float4(acc0[4], acc0[5], acc0[6], acc0[7]);
    *(float4*)(outp + 4096)     = make_float4(acc1[0], acc1[1], acc1[2], acc1[3]);
    *(float4*)(outp + 4096 + 4) = make_float4(acc1[4], acc1[5], acc1[6], acc1[7]);
}

// ---------------- K3: Gram partials: per (b,h,chunk) -> 64 qk + 8 qq + 8 kk ----------------
__global__ __launch_bounds__(256) void k3_gram(const float* __restrict__ qkv2,
                                               float* __restrict__ partial) {
    const int blk = blockIdx.x;
    const int chunk = blk & (NCHUNK - 1);
    const int bh = blk >> 7;                  // 0..15
    const int b = bh >> 3, h = bh & 7;
    const float* qb = qkv2 + ((long long)b * 192 + h * 8) * NPOS;
    const float* kb = qb + 64 * NPOS;
    const int npc = NPOS / NCHUNK;            // 512
    const int n0 = chunk * npc;
    float vals[80];
    #pragma unroll
    for (int s = 0; s < 80; ++s) vals[s] = 0.f;
    for (int t = threadIdx.x; t < npc; t += 256) {
        int n = n0 + t;
        float qv[8], kv[8];
        #pragma unroll
        for (int i = 0; i < 8; ++i) qv[i] = qb[i * NPOS + n];
        #pragma unroll
        for (int j = 0; j < 8; ++j) kv[j] = kb[j * NPOS + n];
        #pragma unroll
        for (int i = 0; i < 8; ++i) {
            #pragma unroll
            for (int j = 0; j < 8; ++j)
                vals[i * 8 + j] = fmaf(qv[i], kv[j], vals[i * 8 + j]);
        }
        #pragma unroll
        for (int i = 0; i < 8; ++i) vals[64 + i] = fmaf(qv[i], qv[i], vals[64 + i]);
        #pragma unroll
        for (int j = 0; j < 8; ++j) vals[72 + j] = fmaf(kv[j], kv[j], vals[72 + j]);
    }
    __shared__ float red[4][80];
    const int lane = threadIdx.x & 63, wv = threadIdx.x >> 6;
    #pragma unroll
    for (int s = 0; s < 80; ++s) {
        float v = vals[s];
        #pragma unroll
        for (int off = 32; off > 0; off >>= 1)
            v += __shfl_xor(v, off, 64);
        if (lane == 0) red[wv][s] = v;
    }
    __syncthreads();
    if (threadIdx.x < 80)
        partial[((long long)bh * NCHUNK + chunk) * 80 + threadIdx.x] =
            red[0][threadIdx.x] + red[1][threadIdx.x] + red[2][threadIdx.x] + red[3][threadIdx.x];
}

// ---------------- K3b: deterministic chunk reduction ----------------
__global__ void k3b_reduce(const float* __restrict__ partial, float* __restrict__ gram) {
    int s = blockIdx.x * 256 + threadIdx.x;
    if (s >= 16 * 80) return;
    int bh = s / 80, slot = s % 80;
    float acc = 0.f;
    for (int c = 0; c < NCHUNK; ++c)
        acc += partial[((long long)bh * NCHUNK + c) * 80 + slot];
    gram[s] = acc;
}

// ---------------- K4: attn -> topk mask softmax -> combined P ----------------
__global__ void k4_combine(const float* __restrict__ gram, const float* __restrict__ temp,
                           const float* __restrict__ aw, float* __restrict__ P) {
    int t = threadIdx.x;               // one (b,h,i) row per thread; 128 threads
    if (t >= 128) return;
    int bh = t >> 3, i = t & 7;
    int h = bh & 7;
    const float* g = gram + bh * 80;
    float qn = fmaxf(sqrtf(g[64 + i]), 1e-12f);
    float tp = temp[h];
    float attn[8];
    #pragma unroll
    for (int j = 0; j < 8; ++j) {
        float kn = fmaxf(sqrtf(g[72 + j]), 1e-12f);
        attn[j] = g[i * 8 + j] / (qn * kn) * tp;
    }
    float awv[4];
    float am = -3.4e38f;
    for (int r = 0; r < 4; ++r) { awv[r] = aw[r]; am = fmaxf(am, awv[r]); }
    float asum = 0.f;
    for (int r = 0; r < 4; ++r) { awv[r] = expf(awv[r] - am); asum += awv[r]; }
    const int kvs[4] = {4, 5, 6, 6};   // int(8*ratio) for 0.5,0.67,0.75,0.8
    float Pacc[8];
    #pragma unroll
    for (int j = 0; j < 8; ++j) Pacc[j] = 0.f;
    for (int r = 0; r < 4; ++r) {
        float sw = awv[r] / asum;
        int kv = kvs[r];
        bool sel[8];
        #pragma unroll
        for (int j = 0; j < 8; ++j) sel[j] = false;
        for (int m = 0; m < kv; ++m) {     // exact top_k: ties -> smallest index
            int best = 0; float bv = -3.4e38f;
            for (int j = 0; j < 8; ++j)
                if (!sel[j] && attn[j] > bv) { bv = attn[j]; best = j; }
            sel[best] = true;
        }
        float mx = -3.4e38f;
        for (int j = 0; j < 8; ++j) if (sel[j]) mx = fmaxf(mx, attn[j]);
        float es = 0.f, e[8];
        for (int j = 0; j < 8; ++j) { e[j] = sel[j] ? expf(attn[j] - mx) : 0.f; es += e[j]; }
        for (int j = 0; j < 8; ++j) Pacc[j] += sw * e[j] / es;
    }
    for (int j = 0; j < 8; ++j) P[t * 8 + j] = Pacc[j];
}

// ---------------- K5: fused tail: weighted -> recalib -> enhanced -> fus(bn2) -> proj ----------------
// block = 64 positions; 256 threads = (16 pos-groups of 4) x (16 ch-groups of 4)
__global__ __launch_bounds__(256) void k5_tail(
        const float* __restrict__ qkv2, const float* __restrict__ x,
        const float* __restrict__ P,
        const float* __restrict__ Wrt, const float* __restrict__ br,
        const float* __restrict__ bn1g, const float* __restrict__ bn1b,
        const float* __restrict__ Wft, const float* __restrict__ bfu,
        const float* __restrict__ bn2g, const float* __restrict__ bn2b,
        const float* __restrict__ Wpt, const float* __restrict__ bp,
        float* __restrict__ out) {
    __shared__ __align__(16) float Xs[64 * 64];
    __shared__ __align__(16) float As[64 * 64];
    __shared__ __align__(16) float Bs[64 * 64];
    __shared__ float Pl[512];
    const int tid = threadIdx.x;
    const int blk = blockIdx.x;
    const int b = blk >> 10;                 // 1024 blocks per batch
    const int n0 = (blk & 1023) << 6;
    const float* vg = qkv2 + ((long long)b * 192 + 128) * NPOS + n0;
    const float* xg = x + ((long long)b * 64) * NPOS + n0;
    #pragma unroll
    for (int k = 0; k < 4; ++k) {
        int idx = tid + k * 256;             // 1024 float4 tiles of [64ch][64pos]
        int ch = idx >> 4, p = (idx & 15) << 2;
        *(float4*)(As + ch * 64 + p) = *(const float4*)(vg + (long long)ch * NPOS + p);
        *(float4*)(Xs + ch * 64 + p) = *(const float4*)(xg + (long long)ch * NPOS + p);
    }
    Pl[tid] = P[b * 512 + tid];
    Pl[tid + 256] = P[b * 512 + 256 + tid];
    __syncthreads();

    const int pg = tid & 15, cg = tid >> 4;
    const int p4 = pg << 2;
    const int hd = cg >> 1;                  // head of our 4 channels
    const float invs = 1.0f / sqrtf(1.0f + 1e-5f);

    // ---- weighted = P @ v  -> Bs
    {
        float acc[4][4];
        #pragma unroll
        for (int u = 0; u < 4; ++u)
            #pragma unroll
            for (int q = 0; q < 4; ++q) acc[u][q] = 0.f;
        #pragma unroll
        for (int j = 0; j < 8; ++j) {
            float4 v4 = *(float4*)(As + (hd * 8 + j) * 64 + p4);
            float vv[4] = {v4.x, v4.y, v4.z, v4.w};
            #pragma unroll
            for (int u = 0; u < 4; ++u) {
                float pv = Pl[hd * 64 + ((4 * cg + u) & 7) * 8 + j];
                #pragma unroll
                for (int q = 0; q < 4; ++q) acc[u][q] = fmaf(pv, vv[q], acc[u][q]);
            }
        }
        #pragma unroll
        for (int u = 0; u < 4; ++u)
            *(float4*)(Bs + (4 * cg + u) * 64 + p4) =
                make_float4(acc[u][0], acc[u][1], acc[u][2], acc[u][3]);
    }
    __syncthreads();

    // ---- recalib = sigmoid(bn1(Wr @ weighted + br)); enhanced -> As
    float rec[4][4];
    {
        float a2[4][4];
        #pragma unroll
        for (int u = 0; u < 4; ++u) {
            float bias = br[4 * cg + u];
            #pragma unroll
            for (int q = 0; q < 4; ++q) a2[u][q] = bias;
        }
        for (int c = 0; c < 64; ++c) {
            float4 bv = *(float4*)(Bs + c * 64 + p4);
            float4 wv = *(const float4*)(Wrt + c * 64 + 4 * cg);
            float bvv[4] = {bv.x, bv.y, bv.z, bv.w};
            float wvv[4] = {wv.x, wv.y, wv.z, wv.w};
            #pragma unroll
            for (int u = 0; u < 4; ++u)
                #pragma unroll
                for (int q = 0; q < 4; ++q)
                    a2[u][q] = fmaf(wvv[u], bvv[q], a2[u][q]);
        }
        #pragma unroll
        for (int u = 0; u < 4; ++u) {
            int oc = 4 * cg + u;
            float s = bn1g[oc] * invs, tt = bn1b[oc];
            #pragma unroll
            for (int q = 0; q < 4; ++q) {
                float z = fmaf(a2[u][q], s, tt);
                rec[u][q] = 1.f / (1.f + expf(-z));
            }
        }
    }
    #pragma unroll
    for (int u = 0; u < 4; ++u) {
        float4 bv = *(float4*)(Bs + (4 * cg + u) * 64 + p4);
        *(float4*)(As + (4 * cg + u) * 64 + p4) =
            make_float4(bv.x * rec[u][0], bv.y * rec[u][1], bv.z * rec[u][2], bv.w * rec[u][3]);
    }
    __syncthreads();

    // ---- fus = bn2(Wf @ [enhanced; x] + bf) -> Bs
    {
        float a2[4][4];
        #pragma unroll
        for (int u = 0; u < 4; ++u) {
            float bias = bfu[4 * cg + u];
            #pragma unroll
            for (int q = 0; q < 4; ++q) a2[u][q] = bias;
        }
        for (int c = 0; c < 64; ++c) {
            float4 av = *(float4*)(As + c * 64 + p4);
            float4 w1 = *(const float4*)(Wft + c * 64 + 4 * cg);
            float avv[4] = {av.x, av.y, av.z, av.w};
            float w1v[4] = {w1.x, w1.y, w1.z, w1.w};
            #pragma unroll
            for (int u = 0; u < 4; ++u)
                #pragma unroll
                for (int q = 0; q < 4; ++q)
                    a2[u][q] = fmaf(w1v[u], avv[q], a2[u][q]);
            float4 xv = *(float4*)(Xs + c * 64 + p4);
            float4 w2 = *(const float4*)(Wft + (64 + c) * 64 + 4 * cg);
            float xvv[4] = {xv.x, xv.y, xv.z, xv.w};
            float w2v[4] = {w2.x, w2.y, w2.z, w2.w};
            #pragma unroll
            for (int u = 0; u < 4; ++u)
                #pragma unroll
                for (int q = 0; q < 4; ++q)
                    a2[u][q] = fmaf(w2v[u], xvv[q], a2[u][q]);
        }
        #pragma unroll
        for (int u = 0; u < 4; ++u) {
            int oc = 4 * cg + u;
            float s = bn2g[oc] * invs, tt = bn2b[oc];
            #pragma unroll
            for (int q = 0; q < 4; ++q) a2[u][q] = fmaf(a2[u][q], s, tt);
            *(float4*)(Bs + oc * 64 + p4) =
                make_float4(a2[u][0], a2[u][1], a2[u][2], a2[u][3]);
        }
    }
    __syncthreads();

    // ---- proj -> out
    {
        float a2[4][4];
        #pragma unroll
        for (int u = 0; u < 4; ++u) {
            float bias = bp[4 * cg + u];
            #pragma unroll
            for (int q = 0; q < 4; ++q) a2[u][q] = bias;
        }
        for (int c = 0; c < 64; ++c) {
            float4 bv = *(float4*)(Bs + c * 64 + p4);
            float4 wv = *(const float4*)(Wpt + c * 64 + 4 * cg);
            float bvv[4] = {bv.x, bv.y, bv.z, bv.w};
            float wvv[4] = {wv.x, wv.y, wv.z, wv.w};
            #pragma unroll
            for (int u = 0; u < 4; ++u)
                #pragma unroll
                for (int q = 0; q < 4; ++q)
                    a2[u][q] = fmaf(wvv[u], bvv[q], a2[u][q]);
        }
        #pragma unroll
        for (int u = 0; u < 4; ++u)
            *(float4*)(out + ((long long)b * 64 + 4 * cg + u) * NPOS + n0 + p4) =
                make_float4(a2[u][0], a2[u][1], a2[u][2], a2[u][3]);
    }
}

extern "C" void kernel_launch(void* const* d_in, const int* in_sizes, int n_in,
                              void* d_out, int out_size, void* d_ws, size_t ws_size,
                              hipStream_t stream) {
    (void)in_sizes; (void)n_in; (void)out_size; (void)ws_size;
    const float* x     = (const float*)d_in[0];
    const float* w_qkv = (const float*)d_in[1];
    const float* b_qkv = (const float*)d_in[2];
    const float* w_dw  = (const float*)d_in[3];
    const float* b_dw  = (const float*)d_in[4];
    const float* temp  = (const float*)d_in[5];
    const float* aw    = (const float*)d_in[6];
    const float* w_rec = (const float*)d_in[7];
    const float* b_rec = (const float*)d_in[8];
    const float* bn1g  = (const float*)d_in[9];
    const float* bn1b  = (const float*)d_in[10];
    const float* w_fus = (const float*)d_in[11];
    const float* b_fus = (const float*)d_in[12];
    const float* bn2g  = (const float*)d_in[13];
    const float* bn2b  = (const float*)d_in[14];
    const float* w_prj = (const float*)d_in[15];
    const float* b_prj = (const float*)d_in[16];
    float* out = (float*)d_out;
    float* ws  = (float*)d_ws;

    float* qkv  = ws;                       // 2*192*65536 = 25165824 floats
    float* qkv2 = qkv + 25165824;           // 25165824 floats
    float* part = qkv2 + 25165824;          // 16*128*80 = 163840
    float* gram = part + 163840;            // 1280
    float* P    = gram + 1280;              // 1024
    float* Wqt  = P + 1024;                 // 12288
    float* Wrt  = Wqt + 12288;              // 4096
    float* Wft  = Wrt + 4096;               // 8192
    float* Wpt  = Wft + 8192;               // 4096  (total ~202.1 MB)

    k0_transpose<<<112, 256, 0, stream>>>(w_qkv, w_rec, w_fus, w_prj, Wqt, Wrt, Wft, Wpt);
    k1_qkv<<<512, 256, 0, stream>>>(x, Wqt, b_qkv, qkv);
    k2_dw<<<6144, 256, 0, stream>>>(qkv, w_dw, b_dw, qkv2);
    k3_gram<<<16 * NCHUNK, 256, 0, stream>>>(qkv2, part);
    k3b_reduce<<<5, 256, 0, stream>>>(part, gram);
    k4_combine<<<1, 128, 0, stream>>>(gram, temp, aw, P);
    k5_tail<<<2048, 256, 0, stream>>>(qkv2, x, P, Wrt, b_rec, bn1g, bn1b,
                                      Wft, b_fus, bn2g, bn2b, Wpt, b_prj, out);
}